// Round 9
// baseline (311.593 us; speedup 1.0000x reference)
//
#include <hip/hip_runtime.h>
#include <hip/hip_fp16.h>
#include <cmath>

// ---------------------------------------------------------------------------
// Self_Attention: B=8, C=256, C_=32, H=W=64, N=4096, GAMMA=1.0
// R13 = R12 collapsed from 5 kernels to 3 (R12 showed prep kernel-time sums
// to ~30us yet prep bill is ~136us -> inter-launch overhead dominates):
//   - cvtw DELETED: tp_proj converts weights f32->f16 on the fly (RTN casts,
//     numerics identical to __float2half; weight f32 loads L2-hot).
//   - pass1b DELETED: pass2 computes sl = -log2(sum of 4 lpart) - SHIFT2
//     inline, prefetched one step ahead exactly as shl was.
//   - tp_proj phases / pass1a / pass2 otherwise byte-identical to R12.
// Launch chain: tp_proj(512) -> pass1a(2048) -> pass2(512).
// ws: ft 2M | gt 2M | hm 16M | lpart 512K   (~21MB)
// ---------------------------------------------------------------------------

#define BN 8
#define CC 256
#define CQ 32
#define NN 4096
#define LPSTEP (BN * NN)

typedef _Float16 half8 __attribute__((ext_vector_type(8)));
typedef _Float16 half4v __attribute__((ext_vector_type(4)));
typedef float f32x4 __attribute__((ext_vector_type(4)));

static __device__ __forceinline__ float fexp2(float x) {
    return __builtin_amdgcn_exp2f(x);
}

#define LOG2E 1.44269504f
#define SHIFT2 28.8539008f   /* 20 * log2(e) */

// sl[j..j+3] = -log2( sum_iq lpart[iq][b][j] ) - SHIFT2   (lpart L2-resident)
static __device__ __forceinline__ f32x4 load_sl(const float* lp, int off) {
    f32x4 s0 = *(const f32x4*)(lp + off);
    f32x4 s1 = *(const f32x4*)(lp + LPSTEP + off);
    f32x4 s2 = *(const f32x4*)(lp + 2 * LPSTEP + off);
    f32x4 s3 = *(const f32x4*)(lp + 3 * LPSTEP + off);
    f32x4 o;
    o.x = -__log2f((s0.x + s1.x) + (s2.x + s3.x)) - SHIFT2;
    o.y = -__log2f((s0.y + s1.y) + (s2.y + s3.y)) - SHIFT2;
    o.z = -__log2f((s0.z + s1.z) + (s2.z + s3.z)) - SHIFT2;
    o.w = -__log2f((s0.w + s1.w) + (s2.w + s3.w)) - SHIFT2;
    return o;
}

// load 8 consecutive f32 and convert (RTN) to half8
static __device__ __forceinline__ half8 ldcvt8(const float* p) {
    f32x4 v0 = *(const f32x4*)(p);
    f32x4 v1 = *(const f32x4*)(p + 4);
    half8 h;
    h[0] = (_Float16)v0.x; h[1] = (_Float16)v0.y;
    h[2] = (_Float16)v0.z; h[3] = (_Float16)v0.w;
    h[4] = (_Float16)v1.x; h[5] = (_Float16)v1.y;
    h[6] = (_Float16)v1.z; h[7] = (_Float16)v1.w;
    return h;
}

// --------------------------------------------------------------------------
// K1: fused transpose + projections (weights converted on the fly).
// Grid 512: b = gid&7, nt = gid>>3.
// Phase A: x-tile prefetched whole (16 f32x4/lane), then 4 rounds of
// T[64][65] transpose -> XT[pix][c^swz] f16 (swz = 8*(pix&7)).
// Phase B1 (f/g): wave w owns pix group 16w+col -> ft/gt[pix][32].
// Phase B2 (h): wave w owns c_out 64w..64w+63 -> hm[c][n].
// --------------------------------------------------------------------------
__global__ __launch_bounds__(256) void tp_proj_kernel(
    const float* __restrict__ x,
    const float* __restrict__ fw, const float* __restrict__ gw,
    const float* __restrict__ hw,
    const float* __restrict__ fb, const float* __restrict__ gb,
    const float* __restrict__ hb,
    __half* __restrict__ ft, __half* __restrict__ gt, __half* __restrict__ hm)
{
    const int tid = threadIdx.x;
    const int w = tid >> 6, lane = tid & 63, col = lane & 15, q = lane >> 4;
    const int gid = blockIdx.x;
    const int b  = gid & 7;
    const int n0 = (gid >> 3) * 64;

    __shared__ float  T[64 * 65];        // 16.6 KB transpose staging
    __shared__ __half XT[64 * 256];      // 32 KB swizzled x-tile [pix][c]

    // ---- phase A: prefetch entire x-tile, then 4 transpose rounds ----
    const int u  = tid >> 4;             // 0..15
    const int n4 = (tid & 15) * 4;
    const int nn = w * 16 + (lane >> 2); // column-read pixel
    const int cc = (lane & 3) * 16;
    const int sA = 8 * (nn & 7);         // write-side swizzle

    f32x4 vx[4][4];
    const float* xb = x + (size_t)b * CC * NN + n0;
#pragma unroll
    for (int c4 = 0; c4 < 4; ++c4)
#pragma unroll
        for (int r = 0; r < 4; ++r)
            vx[c4][r] = __builtin_nontemporal_load(
                (const f32x4*)(xb + (size_t)(c4 * 64 + r * 16 + u) * NN + n4));

#pragma unroll
    for (int c4 = 0; c4 < 4; ++c4) {
        const int c0 = c4 * 64;
#pragma unroll
        for (int r = 0; r < 4; ++r) {
            int c = r * 16 + u;
            T[c * 65 + n4 + 0] = vx[c4][r].x;
            T[c * 65 + n4 + 1] = vx[c4][r].y;
            T[c * 65 + n4 + 2] = vx[c4][r].z;
            T[c * 65 + n4 + 3] = vx[c4][r].w;
        }
        __syncthreads();
        half8 o0, o1;
#pragma unroll
        for (int k = 0; k < 8; ++k) {
            o0[k] = (_Float16)T[(cc + k) * 65 + nn];
            o1[k] = (_Float16)T[(cc + 8 + k) * 65 + nn];
        }
        *(half8*)(void*)(&XT[nn * 256 + ((c0 + cc) ^ sA)])     = o0;
        *(half8*)(void*)(&XT[nn * 256 + ((c0 + cc + 8) ^ sA)]) = o1;
        __syncthreads();
    }

    const f32x4 zero = {0.f, 0.f, 0.f, 0.f};
    const int sw = 8 * (col & 7);        // read-side swizzle (pix&7 = col&7)

    // ---- phase B1: f and g for pix group 16w+col ----
    {
        f32x4 acc[4];
#pragma unroll
        for (int mt = 0; mt < 4; ++mt) acc[mt] = zero;
        const int pixl = 16 * w + col;
#pragma unroll
        for (int ks = 0; ks < 8; ++ks) {
            half8 bf = *(const half8*)(const void*)(
                &XT[pixl * 256 + ((ks * 32 + q * 8) ^ sw)]);
#pragma unroll
            for (int mt = 0; mt < 4; ++mt) {
                const float* wp = (mt < 2) ? (fw + (size_t)(16 * mt + col) * CC)
                                           : (gw + (size_t)(16 * (mt - 2) + col) * CC);
                half8 af = ldcvt8(wp + ks * 32 + q * 8);
                acc[mt] = __builtin_amdgcn_mfma_f32_16x16x32_f16(af, bf, acc[mt], 0, 0, 0);
            }
        }
        const int pix = n0 + pixl;
#pragma unroll
        for (int mt = 0; mt < 4; ++mt) {
            const int mtl = mt & 1;
            const float* bsel = (mt < 2) ? fb : gb;
            __half* dsel = (mt < 2) ? ft : gt;
            half4v hv;
#pragma unroll
            for (int r = 0; r < 4; ++r)
                hv[r] = (_Float16)(acc[mt][r] + bsel[16 * mtl + 4 * q + r]);
            *(half4v*)(void*)(dsel + ((size_t)b * NN + pix) * CQ + 16 * mtl + 4 * q) = hv;
        }
    }

    // ---- phase B2: h for c_out slice 64w..64w+63 ----
    {
        f32x4 acc[4][4];                 // [mt = pix tile][ci = c_out tile]
#pragma unroll
        for (int mt = 0; mt < 4; ++mt)
#pragma unroll
            for (int ci = 0; ci < 4; ++ci) acc[mt][ci] = zero;
#pragma unroll
        for (int ks = 0; ks < 8; ++ks) {
            half8 af[4], bf[4];
#pragma unroll
            for (int mt = 0; mt < 4; ++mt)
                af[mt] = *(const half8*)(const void*)(
                    &XT[(16 * mt + col) * 256 + ((ks * 32 + q * 8) ^ sw)]);
#pragma unroll
            for (int ci = 0; ci < 4; ++ci)
                bf[ci] = ldcvt8(hw + (size_t)(16 * (4 * w + ci) + col) * CC + ks * 32 + q * 8);
#pragma unroll
            for (int mt = 0; mt < 4; ++mt)
#pragma unroll
                for (int ci = 0; ci < 4; ++ci)
                    acc[mt][ci] = __builtin_amdgcn_mfma_f32_16x16x32_f16(
                        af[mt], bf[ci], acc[mt][ci], 0, 0, 0);
        }
#pragma unroll
        for (int ci = 0; ci < 4; ++ci) {
            const int c = 16 * (4 * w + ci) + col;
            const float bias = hb[c];
#pragma unroll
            for (int mt = 0; mt < 4; ++mt) {
                half4v hv;
#pragma unroll
                for (int r = 0; r < 4; ++r)
                    hv[r] = (_Float16)(acc[mt][ci][r] + bias);
                *(half4v*)(void*)(hm + ((size_t)b * CC + c) * NN + n0 + 16 * mt + 4 * q) = hv;
            }
        }
    }
}

// --------------------------------------------------------------------------
// K2: partial softmax column sums.  Grid 2048: b = gid&7, jt = (gid>>3)&63,
// iq = gid>>9 (i-quarter).  lpart[iq][b][j] = sum_{i in quarter} exp2(...).
// --------------------------------------------------------------------------
__global__ __launch_bounds__(256) void pass1a_kernel(
    const __half* __restrict__ ft, const __half* __restrict__ gt,
    float* __restrict__ lpart)
{
    const int tid = threadIdx.x;
    const int w = tid >> 6, lane = tid & 63, col = lane & 15, q = lane >> 4;
    const int gid = blockIdx.x;
    const int b  = gid & 7;
    const int jt = (gid >> 3) & 63;
    const int iq = gid >> 9;             // 0..3
    const int jg = jt * 64 + 16 * w + col;
    const int ibase = iq * 1024;

    const __half* fbase = ft + (size_t)b * NN * CQ;
    half8 gfrag = *(const half8*)(const void*)(gt + ((size_t)b * NN + jg) * CQ + q * 8);

    float a0 = 0.f, a1 = 0.f, a2 = 0.f, a3 = 0.f;
    const f32x4 zero = {0.f, 0.f, 0.f, 0.f};

    half8 a0v = *(const half8*)(const void*)(fbase + (size_t)(ibase + col) * CQ + q * 8);
    half8 a1v = *(const half8*)(const void*)(fbase + (size_t)(ibase + 16 + col) * CQ + q * 8);
    for (int t = 0; t < 32; ++t) {
        int i_n = ibase + ((t + 1) & 31) * 32;
        half8 a2v = *(const half8*)(const void*)(fbase + (size_t)(i_n + col) * CQ + q * 8);
        half8 a3v = *(const half8*)(const void*)(fbase + (size_t)(i_n + 16 + col) * CQ + q * 8);
        f32x4 d0 = __builtin_amdgcn_mfma_f32_16x16x32_f16(a0v, gfrag, zero, 0, 0, 0);
        f32x4 d1 = __builtin_amdgcn_mfma_f32_16x16x32_f16(a1v, gfrag, zero, 0, 0, 0);
        a0 += fexp2(fmaf(d0[0], LOG2E, -SHIFT2)) + fexp2(fmaf(d1[0], LOG2E, -SHIFT2));
        a1 += fexp2(fmaf(d0[1], LOG2E, -SHIFT2)) + fexp2(fmaf(d1[1], LOG2E, -SHIFT2));
        a2 += fexp2(fmaf(d0[2], LOG2E, -SHIFT2)) + fexp2(fmaf(d1[2], LOG2E, -SHIFT2));
        a3 += fexp2(fmaf(d0[3], LOG2E, -SHIFT2)) + fexp2(fmaf(d1[3], LOG2E, -SHIFT2));
        a0v = a2v;
        a1v = a3v;
    }
    float l = (a0 + a1) + (a2 + a3);
    l += __shfl_xor(l, 16);
    l += __shfl_xor(l, 32);
    if (q == 0)
        lpart[((size_t)iq * BN + b) * NN + jg] = l;
}

// --------------------------------------------------------------------------
// K3: O = h @ P^T + x.  R5 structure verbatim (154us champion); the shl
// lookup replaced by inline 4-partial reduce + log2 (prefetched one step
// ahead exactly as shl was).
// --------------------------------------------------------------------------
__global__ __launch_bounds__(256, 2) void pass2_kernel(
    const float* __restrict__ x,
    const __half* __restrict__ ft, const __half* __restrict__ gt,
    const __half* __restrict__ hm, const float* __restrict__ lpart,
    float* __restrict__ out)
{
    const int tid = threadIdx.x;
    const int w = tid >> 6, lane = tid & 63, col = lane & 15, q = lane >> 4;
    const int gid = blockIdx.x;
    const int b  = gid & 7;
    const int i0 = (gid >> 3) * 64;          // 64 i-tiles per batch
    const int cb = 64 * w;                   // wave c-slice: 64 channels

    __shared__ __half P[2][64 * 64];

    const __half* gbase = gt + (size_t)b * NN * CQ;
    const __half* hbase = hm + (size_t)b * CC * NN;
    const float*  lb    = lpart + (size_t)b * NN;   // iq-strided by LPSTEP

    // loop-invariant f B-frags (n = i)
    half8 ffr[4];
#pragma unroll
    for (int it = 0; it < 4; ++it)
        ffr[it] = *(const half8*)(const void*)(ft + ((size_t)b * NN + i0 + 16 * it + col) * CQ + q * 8);

    f32x4 acc[4][4];
#pragma unroll
    for (int ms = 0; ms < 4; ++ms)
#pragma unroll
        for (int ns = 0; ns < 4; ++ns)
            acc[ms][ns] = (f32x4){0.f, 0.f, 0.f, 0.f};

    const f32x4 zero = {0.f, 0.f, 0.f, 0.f};
    const int jml = 16 * w + 4 * q;          // this lane's j offset in the step
    const int sw  = 8 * (col & 7);           // P swizzle for this lane's rows

    // prologue prefetch (step 0)
    half8 gfr = *(const half8*)(const void*)(gbase + (size_t)(16 * w + col) * CQ + q * 8);
    f32x4 sl  = load_sl(lb, jml);

    int buf = 0;
    for (int j0 = 0; j0 < NN; j0 += 64, buf ^= 1) {
        // current-step O-phase B-frags (L2-resident hm), ns=4 x ks=2
        half8 hv[4][2];
#pragma unroll
        for (int ns = 0; ns < 4; ++ns)
#pragma unroll
            for (int ks = 0; ks < 2; ++ks)
                hv[ns][ks] = *(const half8*)(const void*)(
                    hbase + (size_t)(cb + 16 * ns + col) * NN + j0 + ks * 32 + q * 8);

        // S^T tiles: rows j = j0+16w+4q+r, cols i = 16it+col
        f32x4 d[4];
#pragma unroll
        for (int it = 0; it < 4; ++it)
            d[it] = __builtin_amdgcn_mfma_f32_16x16x32_f16(gfr, ffr[it], zero, 0, 0, 0);

        // next-step prefetch (wraps harmlessly on last iter)
        const int jn = (j0 + 64) & (NN - 1);
        half8 gfr_n = *(const half8*)(const void*)(gbase + (size_t)(jn + 16 * w + col) * CQ + q * 8);
        f32x4 sl_n  = load_sl(lb, jn + jml);

        // P = exp2(S*log2e + sl[j])  -> swizzled LDS
        __half* Pb = &P[buf][0];
#pragma unroll
        for (int it = 0; it < 4; ++it) {
            half4v pv;
            pv[0] = (_Float16)fexp2(fmaf(d[it][0], LOG2E, sl[0]));
            pv[1] = (_Float16)fexp2(fmaf(d[it][1], LOG2E, sl[1]));
            pv[2] = (_Float16)fexp2(fmaf(d[it][2], LOG2E, sl[2]));
            pv[3] = (_Float16)fexp2(fmaf(d[it][3], LOG2E, sl[3]));
            *(half4v*)(void*)(Pb + (16 * it + col) * 64 + (jml ^ sw)) = pv;
        }
        __syncthreads();

        // O: A = P (swizzled b128 reads, each feeds 4 MFMAs), B = hv
#pragma unroll
        for (int ks = 0; ks < 2; ++ks) {
            half8 af[4];
#pragma unroll
            for (int ms = 0; ms < 4; ++ms)
                af[ms] = *(const half8*)(const void*)(
                    Pb + (16 * ms + col) * 64 + ((ks * 32 + q * 8) ^ sw));
#pragma unroll
            for (int ms = 0; ms < 4; ++ms)
#pragma unroll
                for (int ns = 0; ns < 4; ++ns)
                    acc[ms][ns] = __builtin_amdgcn_mfma_f32_16x16x32_f16(
                        af[ms], hv[ns][ks], acc[ms][ns], 0, 0, 0);
        }
        gfr = gfr_n;
        sl  = sl_n;
    }

    // epilogue: out = O + x (nontemporal both ways; GAMMA = 1)
    const float* xb = x + (size_t)b * CC * NN;
    float* ob = out + (size_t)b * CC * NN;
#pragma unroll
    for (int ms = 0; ms < 4; ++ms) {
#pragma unroll
        for (int ns = 0; ns < 4; ++ns) {
            int c  = cb + 16 * ns + col;
            int ii = i0 + 16 * ms + 4 * q;
            size_t off = (size_t)c * NN + ii;
            f32x4 xv = __builtin_nontemporal_load((const f32x4*)(xb + off));
            f32x4 ov;
            ov.x = acc[ms][ns][0] + xv.x;
            ov.y = acc[ms][ns][1] + xv.y;
            ov.z = acc[ms][ns][2] + xv.z;
            ov.w = acc[ms][ns][3] + xv.w;
            __builtin_nontemporal_store(ov, (f32x4*)(ob + off));
        }
    }
}

// ---------------------------------------------------------------------------
extern "C" void kernel_launch(void* const* d_in, const int* in_sizes, int n_in,
                              void* d_out, int out_size, void* d_ws, size_t ws_size,
                              hipStream_t stream)
{
    const float* x  = (const float*)d_in[0];
    const float* fw = (const float*)d_in[1];
    const float* fb = (const float*)d_in[2];
    const float* gw = (const float*)d_in[3];
    const float* gb = (const float*)d_in[4];
    const float* hw = (const float*)d_in[5];
    const float* hb = (const float*)d_in[6];
    float* out = (float*)d_out;

    char* ws = (char*)d_ws;
    __half* ft = (__half*)(ws);                          // 2,097,152
    __half* gt = (__half*)(ws + (size_t)2097152);        // 2,097,152
    __half* hm = (__half*)(ws + (size_t)4194304);        // 16,777,216
    float*  lp = (float*) (ws + (size_t)20971520);       //   524,288 (lpart)

    tp_proj_kernel<<<dim3(512), dim3(256), 0, stream>>>(x, fw, gw, hw, fb, gb, hb, ft, gt, hm);
    pass1a_kernel<<<dim3(2048), dim3(256), 0, stream>>>(ft, gt, lp);
    pass2_kernel<<<dim3(512), dim3(256), 0, stream>>>(x, ft, gt, hm, lp, out);
}